// Round 1
// baseline (875.630 us; speedup 1.0000x reference)
//
#include <hip/hip_runtime.h>

#define DEVFN __device__ __forceinline__

static constexpr int BATCH = 8192;

// ---------------------------------------------------------------------------
// Instruction table (precomputed from the reference):
//  p   (i,j,k)  mul n1 n2 din d1 d2   w_off  res_off  j_off  b_off
//  0   (0,0,0)  32  16 16  1  1  1        0       0      0      0
//  1   (0,1,1)  32   8  8  1  3  3     8192     256      1    256
//  2   (0,2,2)  32   4  4  1  5  5    10240     320     10    320
//  3   (1,0,1)  16  16  8  3  1  3    10752     336     35     -
//  4   (1,1,0)  16   8 16  3  3  1    12800     720     44     -
//  5   (1,1,1)  16   8  8  3  3  3    14848    1104     53     -
//  6   (1,1,2)  16   8  4  3  3  5    15872    1296     80     -
//  7   (1,2,1)  16   4  8  3  5  3    16384    1392    125     -
//  8   (1,2,2)  16   4  4  3  5  5    16896    1488    170     -
//  9   (2,0,2)   8  16  4  5  1  5    17152    1536    245     -
// 10   (2,1,1)   8   8  8  5  3  3    17664    1856    270     -
// 11   (2,1,2)   8   8  4  5  3  5    18176    2176    315     -
// 12   (2,2,0)   8   4 16  5  5  1    18432    2336    390     -
// 13   (2,2,1)   8   4  8  5  5  3    18944    2656    415     -
// 14   (2,2,2)   8   4  4  5  5  5    19200    2816    490     -
// x offsets: i=0 -> 0 (32x1), i=1 -> 32 (16x3), i=2 -> 80 (8x5)
// ---------------------------------------------------------------------------

// Stage 1: res[u,v,k] = sum_w W[w,u,v] * x[w,k]  (+ bias for i==0 paths)
template<int MUL, int N1N2, int DIN, int WOFF, int RESOFF, int XOFF, int BOFF>
DEVFN void stage1(const float* __restrict__ wb, const float* __restrict__ bb,
                  const float* xs, float* res, int lane)
{
  if constexpr (N1N2 >= 64) {
    constexpr int C = N1N2 / 64;            // uv pairs per lane (1,2,4)
    float acc[C][DIN];
#pragma unroll
    for (int c = 0; c < C; ++c)
#pragma unroll
      for (int k = 0; k < DIN; ++k) acc[c][k] = 0.f;
    const int uv0 = lane * C;
#pragma unroll 4
    for (int w = 0; w < MUL; ++w) {
      float wv[C];
      if constexpr (C == 4) {
        const float4 t = *reinterpret_cast<const float4*>(wb + WOFF + w * N1N2 + uv0);
        wv[0] = t.x; wv[1] = t.y; wv[2] = t.z; wv[3] = t.w;
      } else if constexpr (C == 2) {
        const float2 t = *reinterpret_cast<const float2*>(wb + WOFF + w * N1N2 + uv0);
        wv[0] = t.x; wv[1] = t.y;
      } else {
        wv[0] = wb[WOFF + w * N1N2 + uv0];
      }
#pragma unroll
      for (int k = 0; k < DIN; ++k) {
        const float xv = xs[XOFF + w * DIN + k];
#pragma unroll
        for (int c = 0; c < C; ++c) acc[c][k] += wv[c] * xv;
      }
    }
    if constexpr (BOFF >= 0) {
#pragma unroll
      for (int c = 0; c < C; ++c) acc[c][0] += bb[BOFF + uv0 + c];
    }
#pragma unroll
    for (int c = 0; c < C; ++c)
#pragma unroll
      for (int k = 0; k < DIN; ++k)
        res[RESOFF + (uv0 + c) * DIN + k] = acc[c][k];
  } else {
    // n1*n2 < 64: R lanes share one uv, each takes a w-subset, reduce at end.
    constexpr int R  = 64 / N1N2;
    constexpr int SH = (N1N2 == 32) ? 5 : 4;
    float acc[DIN];
#pragma unroll
    for (int k = 0; k < DIN; ++k) acc[k] = 0.f;
    const int uv = lane & (N1N2 - 1);
    const int w0 = lane >> SH;
#pragma unroll
    for (int t = 0; t < MUL / R; ++t) {
      const float wv = wb[WOFF + t * 64 + lane];   // flat coalesced
      const int w = t * R + w0;
#pragma unroll
      for (int k = 0; k < DIN; ++k) acc[k] += wv * xs[XOFF + w * DIN + k];
    }
    if constexpr (N1N2 <= 16) {
#pragma unroll
      for (int k = 0; k < DIN; ++k) acc[k] += __shfl_xor(acc[k], 16);
    }
#pragma unroll
    for (int k = 0; k < DIN; ++k) acc[k] += __shfl_xor(acc[k], 32);
    if (w0 == 0) {
      if constexpr (BOFF >= 0) acc[0] += bb[BOFF + uv];
#pragma unroll
      for (int k = 0; k < DIN; ++k) res[RESOFF + uv * DIN + k] = acc[k];
    }
  }
}

// Stage 2: one output cell (j,k): out[u*D1+di, v*D2+dj] =
//   sum_p (1/M_p) * sum_k3 w3j_p[di,dj,k3] * res_p[u,v,k3]
template<int ROW0, int COL0, int NU, int D1, int NV, int D2,
         int R0, int DI0, int J0, int M0,
         int R1, int DI1, int J1, int M1,
         int R2, int DI2, int J2, int M2>
DEVFN void cell_out(const float* res, const float* w3, float* outb, int lane)
{
  constexpr int ROWS = NU * D1;
  constexpr int COLS = NV * D2;
  constexpr int SZ = ROWS * COLS;
  for (int e = lane; e < SZ; e += 64) {
    const int rr = e / COLS;
    const int cc = e - rr * COLS;
    const int u = rr / D1, di = rr - u * D1;
    const int v = cc / D2, dj = cc - v * D2;
    float acc = 0.f;
    {
      float s = 0.f;
#pragma unroll
      for (int k3 = 0; k3 < DI0; ++k3)
        s += w3[J0 + (di * D2 + dj) * DI0 + k3] * res[R0 + (u * NV + v) * DI0 + k3];
      acc += s * (1.f / (float)M0);
    }
    if constexpr (R1 >= 0) {
      float s = 0.f;
#pragma unroll
      for (int k3 = 0; k3 < DI1; ++k3)
        s += w3[J1 + (di * D2 + dj) * DI1 + k3] * res[R1 + (u * NV + v) * DI1 + k3];
      acc += s * (1.f / (float)M1);
    }
    if constexpr (R2 >= 0) {
      float s = 0.f;
#pragma unroll
      for (int k3 = 0; k3 < DI2; ++k3)
        s += w3[J2 + (di * D2 + dj) * DI2 + k3] * res[R2 + (u * NV + v) * DI2 + k3];
      acc += s * (1.f / (float)M2);
    }
    outb[(ROW0 + rr) * 60 + (COL0 + cc)] = acc;
  }
}

__global__ __launch_bounds__(256)
void expansion_kernel(const float* __restrict__ x_in,
                      const float* __restrict__ weights,
                      const float* __restrict__ bias,
                      const float* __restrict__ w3j,
                      float* __restrict__ out)
{
  __shared__ __align__(16) float lds_x[4][120];
  __shared__ __align__(16) float lds_res[4][2896];
  __shared__ __align__(16) float lds_w3j[615];

  const int wave = threadIdx.x >> 6;
  const int lane = threadIdx.x & 63;
  const int b = blockIdx.x * 4 + wave;

  // stage w3j (block-common) and x (per-wave) into LDS
  for (int t = threadIdx.x; t < 615; t += 256) lds_w3j[t] = w3j[t];
  const float* xb = x_in + (size_t)b * 120;
  if (lane < 30)
    *reinterpret_cast<float4*>(&lds_x[wave][lane * 4]) =
        *reinterpret_cast<const float4*>(xb + lane * 4);
  __syncthreads();

  const float* wb = weights + (size_t)b * 19328;
  const float* bb = bias + (size_t)b * 336;
  const float* xs = lds_x[wave];
  float* res = lds_res[wave];

  // ---- stage 1: 15 instructions -------------------------------------------
  //      MUL N1N2 DIN  WOFF  RESOFF XOFF BOFF
  stage1<32, 256, 1,     0,      0,   0,    0>(wb, bb, xs, res, lane); // p0
  stage1<32,  64, 1,  8192,    256,   0,  256>(wb, bb, xs, res, lane); // p1
  stage1<32,  16, 1, 10240,    320,   0,  320>(wb, bb, xs, res, lane); // p2
  stage1<16, 128, 3, 10752,    336,  32,   -1>(wb, bb, xs, res, lane); // p3
  stage1<16, 128, 3, 12800,    720,  32,   -1>(wb, bb, xs, res, lane); // p4
  stage1<16,  64, 3, 14848,   1104,  32,   -1>(wb, bb, xs, res, lane); // p5
  stage1<16,  32, 3, 15872,   1296,  32,   -1>(wb, bb, xs, res, lane); // p6
  stage1<16,  32, 3, 16384,   1392,  32,   -1>(wb, bb, xs, res, lane); // p7
  stage1<16,  16, 3, 16896,   1488,  32,   -1>(wb, bb, xs, res, lane); // p8
  stage1< 8,  64, 5, 17152,   1536,  80,   -1>(wb, bb, xs, res, lane); // p9
  stage1< 8,  64, 5, 17664,   1856,  80,   -1>(wb, bb, xs, res, lane); // p10
  stage1< 8,  32, 5, 18176,   2176,  80,   -1>(wb, bb, xs, res, lane); // p11
  stage1< 8,  64, 5, 18432,   2336,  80,   -1>(wb, bb, xs, res, lane); // p12
  stage1< 8,  32, 5, 18944,   2656,  80,   -1>(wb, bb, xs, res, lane); // p13
  stage1< 8,  16, 5, 19200,   2816,  80,   -1>(wb, bb, xs, res, lane); // p14

  __syncthreads();

  // ---- stage 2: 9 output cells --------------------------------------------
  float* outb = out + (size_t)b * 3600;
  //       R0 C0  NU D1 NV D2   res din joff mul  (up to 3 instructions)
  cell_out< 0,  0, 16, 1, 16, 1,    0, 1,   0, 32,  -1, 1, 0, 1,  -1, 1, 0, 1>(res, lds_w3j, outb, lane); // (0,0): p0
  cell_out< 0, 16, 16, 1,  8, 3,  336, 3,  35, 16,  -1, 1, 0, 1,  -1, 1, 0, 1>(res, lds_w3j, outb, lane); // (0,1): p3
  cell_out< 0, 40, 16, 1,  4, 5, 1536, 5, 245,  8,  -1, 1, 0, 1,  -1, 1, 0, 1>(res, lds_w3j, outb, lane); // (0,2): p9
  cell_out<16,  0,  8, 3, 16, 1,  720, 3,  44, 16,  -1, 1, 0, 1,  -1, 1, 0, 1>(res, lds_w3j, outb, lane); // (1,0): p4
  cell_out<16, 16,  8, 3,  8, 3,  256, 1,   1, 32, 1104, 3,  53, 16, 1856, 5, 270, 8>(res, lds_w3j, outb, lane); // (1,1): p1,p5,p10
  cell_out<16, 40,  8, 3,  4, 5, 1296, 3,  80, 16, 2176, 5, 315,  8,  -1, 1, 0, 1>(res, lds_w3j, outb, lane); // (1,2): p6,p11
  cell_out<40,  0,  4, 5, 16, 1, 2336, 5, 390,  8,  -1, 1, 0, 1,  -1, 1, 0, 1>(res, lds_w3j, outb, lane); // (2,0): p12
  cell_out<40, 16,  4, 5,  8, 3, 1392, 3, 125, 16, 2656, 5, 415,  8,  -1, 1, 0, 1>(res, lds_w3j, outb, lane); // (2,1): p7,p13
  cell_out<40, 40,  4, 5,  4, 5,  320, 1,  10, 32, 1488, 3, 170, 16, 2816, 5, 490, 8>(res, lds_w3j, outb, lane); // (2,2): p2,p8,p14
}

extern "C" void kernel_launch(void* const* d_in, const int* in_sizes, int n_in,
                              void* d_out, int out_size, void* d_ws, size_t ws_size,
                              hipStream_t stream) {
  const float* x_in = (const float*)d_in[0];
  const float* weights = (const float*)d_in[1];
  const float* bias = (const float*)d_in[2];
  const float* w3j = (const float*)d_in[3];
  float* out = (float*)d_out;
  expansion_kernel<<<dim3(BATCH / 4), dim3(256), 0, stream>>>(x_in, weights, bias, w3j, out);
}